// Round 1
// baseline (467.413 us; speedup 1.0000x reference)
//
#include <hip/hip_runtime.h>
#include <hip/hip_bf16.h>
#include <math.h>

// MoE noisy-top1 gating:
//   clean = input @ w_gate            [N,3]
//   raw   = input @ w_noise           [N,3]
//   std   = softplus(raw) + 0.2
//   logit = clean + noise * std
//   out   = argmax_e(logit)  (int32, lowest index on ties)
//
// N=262144 tokens, D=256, E=3. Memory-bound: ~272 MB traffic -> ~43 us roofline.
// One wave per token: lane i loads float4 of the row (1 KiB/wave, fully
// coalesced), 24 FMAs/lane, 6-value butterfly reduce, lane 0 finishes.

#define NTOK 262144
#define DDIM 256
#define NEXP 3
#define NOISE_EPS 0.2f

__device__ __forceinline__ float wave_sum64(float v) {
    v += __shfl_xor(v, 32);
    v += __shfl_xor(v, 16);
    v += __shfl_xor(v, 8);
    v += __shfl_xor(v, 4);
    v += __shfl_xor(v, 2);
    v += __shfl_xor(v, 1);
    return v;
}

__device__ __forceinline__ float softplus_stable(float x) {
    // log(1+exp(x)) = max(x,0) + log1p(exp(-|x|))   (matches jax.nn.softplus)
    return fmaxf(x, 0.0f) + log1pf(expf(-fabsf(x)));
}

__global__ __launch_bounds__(256) void moe_gate_kernel(
    const float* __restrict__ input,    // [N, D]
    const float* __restrict__ w_gate,   // [D, E] row-major
    const float* __restrict__ w_noise,  // [D, E] row-major
    const float* __restrict__ noise,    // [N, E]
    int* __restrict__ out)              // [N]
{
    const int lane        = threadIdx.x & 63;
    const int wavesPerBlk = blockDim.x >> 6;
    const int waveId      = blockIdx.x * wavesPerBlk + (threadIdx.x >> 6);
    const int numWaves    = gridDim.x * wavesPerBlk;

    // Lane i covers d = 4*lane .. 4*lane+3. Weights [D,E] flat = d*3+e, so this
    // lane's 12 floats are contiguous at 12*lane -> three float4 loads.
    const float4* wg4 = (const float4*)w_gate;
    const float4* wn4 = (const float4*)w_noise;
    const float4 wg0 = wg4[lane * 3 + 0];  // {d0e0 d0e1 d0e2 d1e0}
    const float4 wg1 = wg4[lane * 3 + 1];  // {d1e1 d1e2 d2e0 d2e1}
    const float4 wg2 = wg4[lane * 3 + 2];  // {d2e2 d3e0 d3e1 d3e2}
    const float4 wn0 = wn4[lane * 3 + 0];
    const float4 wn1 = wn4[lane * 3 + 1];
    const float4 wn2 = wn4[lane * 3 + 2];

    const int tokensPerWave = NTOK / numWaves;   // grid chosen so this divides
    const int tBeg = waveId * tokensPerWave;
    const int tEnd = tBeg + tokensPerWave;

    for (int t = tBeg; t < tEnd; ++t) {
        const float4 x = ((const float4*)(input + (size_t)t * DDIM))[lane];

        float g0 = fmaf(x.x, wg0.x, fmaf(x.y, wg0.w, fmaf(x.z, wg1.z, x.w * wg2.y)));
        float g1 = fmaf(x.x, wg0.y, fmaf(x.y, wg1.x, fmaf(x.z, wg1.w, x.w * wg2.z)));
        float g2 = fmaf(x.x, wg0.z, fmaf(x.y, wg1.y, fmaf(x.z, wg2.x, x.w * wg2.w)));
        float n0 = fmaf(x.x, wn0.x, fmaf(x.y, wn0.w, fmaf(x.z, wn1.z, x.w * wn2.y)));
        float n1 = fmaf(x.x, wn0.y, fmaf(x.y, wn1.x, fmaf(x.z, wn1.w, x.w * wn2.z)));
        float n2 = fmaf(x.x, wn0.z, fmaf(x.y, wn1.y, fmaf(x.z, wn2.x, x.w * wn2.w)));

        g0 = wave_sum64(g0);
        g1 = wave_sum64(g1);
        g2 = wave_sum64(g2);
        n0 = wave_sum64(n0);
        n1 = wave_sum64(n1);
        n2 = wave_sum64(n2);

        if (lane == 0) {
            const float* nz = noise + (size_t)t * NEXP;
            float l0 = fmaf(nz[0], softplus_stable(n0) + NOISE_EPS, g0);
            float l1 = fmaf(nz[1], softplus_stable(n1) + NOISE_EPS, g1);
            float l2 = fmaf(nz[2], softplus_stable(n2) + NOISE_EPS, g2);
            int best = 0;
            float bv = l0;
            if (l1 > bv) { bv = l1; best = 1; }
            if (l2 > bv) { bv = l2; best = 2; }
            out[t] = best;
        }
    }
}

extern "C" void kernel_launch(void* const* d_in, const int* in_sizes, int n_in,
                              void* d_out, int out_size, void* d_ws, size_t ws_size,
                              hipStream_t stream) {
    const float* input   = (const float*)d_in[0];
    const float* w_gate  = (const float*)d_in[1];
    const float* w_noise = (const float*)d_in[2];
    const float* noise   = (const float*)d_in[3];
    int* out = (int*)d_out;

    // 2048 blocks x 256 thr = 8192 waves -> 32 tokens/wave; 8 blocks/CU.
    dim3 grid(2048), block(256);
    moe_gate_kernel<<<grid, block, 0, stream>>>(input, w_gate, w_noise, noise, out);
}

// Round 2
// 391.428 us; speedup vs baseline: 1.1941x; 1.1941x over previous
//
#include <hip/hip_runtime.h>
#include <hip/hip_bf16.h>
#include <math.h>

// MoE noisy-top1 gating:
//   clean = input @ w_gate            [N,3]
//   raw   = input @ w_noise           [N,3]
//   std   = softplus(raw) + 0.2
//   logit = clean + noise * std
//   out   = argmax_e(logit)  (int32, lowest index on ties)
//
// N=262144 tokens, D=256, E=3. Memory-bound floor ~43 us (272 MB @ 6.3 TB/s).
//
// R1 post-mortem: one-wave-per-token + 6x full-64-lane butterflies was
// latency-bound on the serialized ds_swizzle chain (36 dependent steps/token,
// 216 us, 8% HBM). R2: 8 lanes per token -> wave processes 8 tokens at once,
// butterfly is 3 steps (xor 1,2,4) amortized over 8 tokens. Epilogue computed
// redundantly by all lanes of the 8-lane group (butterfly leaves full sums in
// every lane) so only the final store is divergent.

#define NTOK 262144
#define DDIM 256
#define NEXP 3
#define NOISE_EPS 0.2f

__device__ __forceinline__ float softplus_stable(float x) {
    // log(1+exp(x)) = max(x,0) + log1p(exp(-|x|))   (matches jax.nn.softplus)
    return fmaxf(x, 0.0f) + log1pf(expf(-fabsf(x)));
}

__global__ __launch_bounds__(256) void moe_gate_kernel(
    const float* __restrict__ input,    // [N, D]
    const float* __restrict__ w_gate,   // [D, E] row-major
    const float* __restrict__ w_noise,  // [D, E] row-major
    const float* __restrict__ noise,    // [N, E]
    int* __restrict__ out)              // [N]
{
    const int lane = threadIdx.x & 63;
    const int s    = lane & 7;    // sublane within token: covers dims 32p+4s..+3
    const int g    = lane >> 3;   // token slot within wave (8 tokens concurrent)

    const int wavesPerBlk = blockDim.x >> 6;
    const int waveId      = blockIdx.x * wavesPerBlk + (threadIdx.x >> 6);

    // 8192 waves x 32 tokens = 262144. 4 groups of 8 tokens per wave.
    const int tBase0 = waveId * 32;

    const float4* in4 = (const float4*)input;   // row = 64 float4s
    const float4* wg4 = (const float4*)w_gate;  // [D*E/4] = 192 float4s
    const float4* wn4 = (const float4*)w_noise;

    #pragma unroll
    for (int grp = 0; grp < 4; ++grp) {
        const int t = tBase0 + grp * 8 + g;

        float g0 = 0.f, g1 = 0.f, g2 = 0.f;
        float n0 = 0.f, n1 = 0.f, n2 = 0.f;

        #pragma unroll
        for (int p = 0; p < 8; ++p) {
            // dims d0 = 32p + 4s .. +3 ; input float4 idx = t*64 + 8p + s
            const float4 x = in4[(size_t)t * 64 + p * 8 + s];
            // weights for these 4 dims: 12 contiguous floats at float4 idx 3*(8p+s)
            const int wi = 3 * (p * 8 + s);
            const float4 wg0 = wg4[wi + 0];  // {d0e0 d0e1 d0e2 d1e0}
            const float4 wg1 = wg4[wi + 1];  // {d1e1 d1e2 d2e0 d2e1}
            const float4 wg2 = wg4[wi + 2];  // {d2e2 d3e0 d3e1 d3e2}
            const float4 wn0 = wn4[wi + 0];
            const float4 wn1 = wn4[wi + 1];
            const float4 wn2 = wn4[wi + 2];

            g0 = fmaf(x.x, wg0.x, fmaf(x.y, wg0.w, fmaf(x.z, wg1.z, fmaf(x.w, wg2.y, g0))));
            g1 = fmaf(x.x, wg0.y, fmaf(x.y, wg1.x, fmaf(x.z, wg1.w, fmaf(x.w, wg2.z, g1))));
            g2 = fmaf(x.x, wg0.z, fmaf(x.y, wg1.y, fmaf(x.z, wg2.x, fmaf(x.w, wg2.w, g2))));
            n0 = fmaf(x.x, wn0.x, fmaf(x.y, wn0.w, fmaf(x.z, wn1.z, fmaf(x.w, wn2.y, n0))));
            n1 = fmaf(x.x, wn0.y, fmaf(x.y, wn1.x, fmaf(x.z, wn1.w, fmaf(x.w, wn2.z, n1))));
            n2 = fmaf(x.x, wn0.z, fmaf(x.y, wn1.y, fmaf(x.z, wn2.x, fmaf(x.w, wn2.w, n2))));
        }

        // Reduce across the 8 sublanes of each token group (3 butterfly steps,
        // all 8 tokens of the wave reduced simultaneously). Every lane ends up
        // holding the full sums for its token.
        #pragma unroll
        for (int st = 1; st < 8; st <<= 1) {
            g0 += __shfl_xor(g0, st);
            g1 += __shfl_xor(g1, st);
            g2 += __shfl_xor(g2, st);
            n0 += __shfl_xor(n0, st);
            n1 += __shfl_xor(n1, st);
            n2 += __shfl_xor(n2, st);
        }

        // Epilogue: all lanes of the group compute (no divergence); s==0 stores.
        const float* nz = noise + (size_t)t * NEXP;
        const float l0 = fmaf(nz[0], softplus_stable(n0) + NOISE_EPS, g0);
        const float l1 = fmaf(nz[1], softplus_stable(n1) + NOISE_EPS, g1);
        const float l2 = fmaf(nz[2], softplus_stable(n2) + NOISE_EPS, g2);

        int best = 0;
        float bv = l0;
        if (l1 > bv) { bv = l1; best = 1; }
        if (l2 > bv) { bv = l2; best = 2; }
        if (s == 0) out[t] = best;
    }
}

extern "C" void kernel_launch(void* const* d_in, const int* in_sizes, int n_in,
                              void* d_out, int out_size, void* d_ws, size_t ws_size,
                              hipStream_t stream) {
    const float* input   = (const float*)d_in[0];
    const float* w_gate  = (const float*)d_in[1];
    const float* w_noise = (const float*)d_in[2];
    const float* noise   = (const float*)d_in[3];
    int* out = (int*)d_out;

    // 2048 blocks x 256 thr = 8192 waves -> 32 tokens/wave; 8 blocks/CU.
    dim3 grid(2048), block(256);
    moe_gate_kernel<<<grid, block, 0, stream>>>(input, w_gate, w_noise, noise, out);
}